// Round 8
// baseline (56.164 us; speedup 1.0000x reference)
//
#include <hip/hip_runtime.h>
#include <math.h>

#define BSZ 320
#define N2  640
#define DIM 128
#define GAM (1.0/0.07)

__device__ __forceinline__ double wave_red(double v) {
    #pragma unroll
    for (int off = 32; off > 0; off >>= 1) v += __shfl_down(v, off, 64);
    return v;
}

// --- K1: raw transpose z -> znT4 (layout: [k4][row][4] floats), zero ticket counter ---
__launch_bounds__(256)
__global__ void k_tr(const float* __restrict__ z, float* __restrict__ znT4,
                     int* __restrict__ counter) {
    const int tid = threadIdx.x;            // 256
    const int row = blockIdx.x * 2 + (tid >> 7);   // 320 blocks -> rows 2b, 2b+1
    const int k   = tid & 127;
    if (blockIdx.x == 0 && tid == 0) *counter = 0;
    znT4[(k >> 2) * (N2 * 4) + row * 4 + (k & 3)] = z[row * DIM + k];
}

// --- K2: gram rows. Block t: E[t][i] = KK(t,i) (zero diag) and Kn[t][i] = K[i,320+t],
// via raw f32 dots + f64 norm factorization. Also rE[t], ssq[t]. No inner barriers. ---
__launch_bounds__(320)
__global__ void k_gram(const float* __restrict__ z, const float* __restrict__ znT4,
                       float* __restrict__ E32, float* __restrict__ Kn32,
                       double* __restrict__ rE, double* __restrict__ ssq) {
    const int t = blockIdx.x, tid = threadIdx.x;   // 320 x 320
    const int wave = tid >> 6, lane = tid & 63;
    __shared__ float zA[DIM], zB[DIM];             // raw rows t, 320+t
    __shared__ double s2[5];
    __shared__ double snrm[2];
    __shared__ double sred[5][2];

    // stage rows t and 320+t (threads 0..255), accumulate their norms
    double w = 0.0;
    if (tid < 256) {
        int r = tid >> 7, k = tid & 127;
        float v = z[(r == 0 ? t : BSZ + t) * DIM + k];
        if (r == 0) zA[k] = v; else zB[k] = v;
        w = (double)v * (double)v;
    }
    w = wave_red(w);                    // waves 0,1 = row A halves; 2,3 = row B
    if (lane == 0) s2[wave] = w;
    __syncthreads();
    if (tid == 0) {
        snrm[0] = 1.0 / sqrt(s2[0] + s2[1]);
        snrm[1] = 1.0 / sqrt(s2[2] + s2[3]);
    }
    __syncthreads();

    // main loop: coalesced float4 loads of znT4 column tid; own-column norm in f64
    const float4* znv = (const float4*)znT4;
    const float4* zAv = (const float4*)zA;
    const float4* zBv = (const float4*)zB;
    float cA = 0.f, cB = 0.f;
    double rr = 0.0;
    #pragma unroll
    for (int k4 = 0; k4 < 32; k4++) {
        float4 v = znv[k4 * N2 + tid];
        float4 a = zAv[k4];             // LDS broadcast
        float4 b = zBv[k4];             // LDS broadcast
        cA = fmaf(a.x, v.x, cA); cB = fmaf(b.x, v.x, cB);
        rr = fma((double)v.x, (double)v.x, rr);
        cA = fmaf(a.y, v.y, cA); cB = fmaf(b.y, v.y, cB);
        rr = fma((double)v.y, (double)v.y, rr);
        cA = fmaf(a.z, v.z, cA); cB = fmaf(b.z, v.z, cB);
        rr = fma((double)v.z, (double)v.z, rr);
        cA = fmaf(a.w, v.w, cA); cB = fmaf(b.w, v.w, cB);
        rr = fma((double)v.w, (double)v.w, rr);
    }
    double sI = 1.0 / sqrt(rr);
    double cosA = (double)cA * snrm[0] * sI;
    double cosB = (double)cB * snrm[1] * sI;
    double Et = (tid == t) ? 0.0 : exp(-GAM * (2.0 - 2.0 * cosA));
    double kn = exp(-GAM * (2.0 - 2.0 * cosB));    // K[tid, 320+t]
    E32[t * BSZ + tid]  = (float)Et;
    Kn32[t * BSZ + tid] = (float)kn;

    double se = wave_red(Et);
    double sq = wave_red(Et * Et);
    if (lane == 0) { sred[wave][0] = se; sred[wave][1] = sq; }
    __syncthreads();
    if (tid == 0) {
        double a0 = 0.0, a1 = 0.0;
        for (int ww = 0; ww < 5; ww++) { a0 += sred[ww][0]; a1 += sred[ww][1]; }
        rE[t] = a0; ssq[t] = a1;
    }
}

// --- K3: per-t coef + final pass; non-atomic partials + ticket; last block outputs ---
__launch_bounds__(320)
__global__ void k_cf(const float* __restrict__ E32, const float* __restrict__ Kn32,
                     const double* __restrict__ rE, const double* __restrict__ ssq,
                     double* __restrict__ partials, int* __restrict__ counter,
                     float* __restrict__ out) {
    const int t = blockIdx.x, tid = threadIdx.x;   // 320 x 320
    const int wave = tid >> 6, lane = tid & 63;
    __shared__ double sred[5][7];
    __shared__ double sc[8];
    __shared__ int lastflag;
    const double a = 1.0 / 1.1, c = 1.0 / 321.1;
    const double q = 1.0 - 320.0 * c;

    double rEi  = rE[tid];
    double Ereg = (double)E32[t * BSZ + tid];
    double kn   = (double)Kn32[t * BSZ + tid];
    if (tid == t) sc[6] = kn;                      // posterm_t = K[t, 320+t]

    // block reduce: S = sum rE, mv = E[t,:].rE
    {
        double s1 = wave_red(rEi);
        double s2 = wave_red(Ereg * rEi);
        if (lane == 0) { sred[wave][0] = s1; sred[wave][1] = s2; }
    }
    __syncthreads();
    if (tid == 0) {
        double S = 0, mv = 0;
        for (int w = 0; w < 5; w++) { S += sred[w][0]; mv += sred[w][1]; }
        double rEt = rE[t], ssqt = ssq[t];
        double pt  = a * q - a * a * q * (rEt - c * S);
        double b   = 320.0 * a * q - a * a * q * q * S;
        double up  = a * q * rEt - a * a * q * (mv - c * S * rEt);
        double sc1 = a * ssqt - a * c * rEt * rEt;
        double Wtt = -a * c * rEt;
        double Mtt = a * (1.0 - c) - a * a * (c * c * S - 2.0 * c * rEt);
        double s11 = 1.0 - up, s12 = -b, s21 = -sc1, s22 = 1.0 - up;
        double det = s11 * s22 - s12 * s21;
        double r1 = 2.0 * b, r2 = 2.0 * up;
        double be1 = (s22 * r1 - s12 * r2) / det;
        double be2 = (s11 * r2 - s21 * r1) / det;
        double g1  = (s22 * pt - s12 * Wtt) / det;
        double g2  = (s11 * Wtt - s21 * pt) / det;
        double ytt = 2.0 * pt + be1 * Wtt + be2 * pt;
        double dt  = Mtt + g1 * Wtt + g2 * pt;
        double rho = ytt / dt;
        sc[0] = rEt;
        sc[1] = S;
        sc[2] = 2.0 + be2 - rho * g2;   // cP
        sc[3] = be1 - rho * g1;         // cW
        sc[4] = -rho;                   // cM
    }
    __syncthreads();

    // final per-(t, i=tid) pass
    {
        double rEt = sc[0], S = sc[1], cP = sc[2], cW = sc[3], cM = sc[4];
        double s_neg = 0, s_al = 0, s_kn = 0, cz = 0, c1v = 0, cpos = 0;
        if (tid != t) {
            double p_i = a * q - a * a * q * (rEi - c * S);
            double V   = a * Ereg - a * c * rEt;
            double Mi  = -a * c - a * a * (Ereg - c * (rEt + rEi) + c * c * S);
            double x = cP * p_i + cW * V + cM * Mi;
            double alpha = fmin(fmax(x, 0.0), 1.0);
            s_neg = alpha * kn; s_al = alpha; s_kn = kn;
            cz   = (x <= 0.0) ? 1.0 : 0.0;
            c1v  = (x >= 1.0) ? 1.0 : 0.0;
            cpos = (x > 0.0) ? 1.0 : 0.0;
        }
        s_neg = wave_red(s_neg); s_al = wave_red(s_al); s_kn = wave_red(s_kn);
        cz = wave_red(cz); c1v = wave_red(c1v); cpos = wave_red(cpos);
        if (lane == 0) {
            sred[wave][0] = s_neg; sred[wave][1] = s_al; sred[wave][2] = s_kn;
            sred[wave][3] = cz;    sred[wave][4] = c1v;  sred[wave][5] = cpos;
        }
    }
    __syncthreads();
    if (tid == 0) {
        double a0 = 0, a1 = 0, a2 = 0, a3 = 0, a4 = 0, a5 = 0;
        for (int w = 0; w < 5; w++) {
            a0 += sred[w][0]; a1 += sred[w][1]; a2 += sred[w][2];
            a3 += sred[w][3]; a4 += sred[w][4]; a5 += sred[w][5];
        }
        partials[t * 8 + 0] = a0;
        partials[t * 8 + 1] = a1 * sc[6];
        partials[t * 8 + 2] = a2;
        partials[t * 8 + 3] = a3;
        partials[t * 8 + 4] = a4;
        partials[t * 8 + 5] = a5;
        partials[t * 8 + 6] = sc[6];
        __threadfence();
        int ticket = atomicAdd(counter, 1);
        lastflag = (ticket == BSZ - 1) ? 1 : 0;
    }
    __syncthreads();

    // last block: global reduce of partials -> 6 f32 outputs
    if (lastflag) {
        __threadfence();
        double v0 = partials[tid * 8 + 0], v1 = partials[tid * 8 + 1];
        double v2 = partials[tid * 8 + 2], v3 = partials[tid * 8 + 3];
        double v4 = partials[tid * 8 + 4], v5 = partials[tid * 8 + 5];
        double v6 = partials[tid * 8 + 6];
        v0 = wave_red(v0); v1 = wave_red(v1); v2 = wave_red(v2);
        v3 = wave_red(v3); v4 = wave_red(v4); v5 = wave_red(v5);
        v6 = wave_red(v6);
        if (lane == 0) {
            sred[wave][0] = v0; sred[wave][1] = v1; sred[wave][2] = v2;
            sred[wave][3] = v3; sred[wave][4] = v4; sred[wave][5] = v5;
            sred[wave][6] = v6;
        }
        __syncthreads();
        if (tid == 0) {
            double b0 = 0, b1 = 0, b2 = 0, b3 = 0, b4 = 0, b5 = 0, b6 = 0;
            for (int w = 0; w < 5; w++) {
                b0 += sred[w][0]; b1 += sred[w][1]; b2 += sred[w][2];
                b3 += sred[w][3]; b4 += sred[w][4]; b5 += sred[w][5];
                b6 += sred[w][6];
            }
            out[0] = (float)((b0 - b1) / 320.0);        // loss
            out[1] = (float)(b6 / 320.0);               // pos_terms.mean()
            out[2] = (float)(b2 / (319.0 * 320.0));     // Kn.mean()
            out[3] = (float)(b4 / (b5 + 1e-10));        // sparsity
            out[4] = (float)(b3 / (320.0 * 319.0));     // num_zero
            out[5] = 0.0f;
        }
    }
}

extern "C" void kernel_launch(void* const* d_in, const int* in_sizes, int n_in,
                              void* d_out, int out_size, void* d_ws, size_t ws_size,
                              hipStream_t stream) {
    const float* z = (const float*)d_in[0];
    float* out = (float*)d_out;
    char* ws = (char*)d_ws;

    float*  znT4     = (float*)(ws);                       // 327680 B
    float*  E32      = (float*)(ws + 327680);              // 409600 B
    float*  Kn32     = (float*)(ws + 737280);              // 409600 B
    double* rE       = (double*)(ws + 1146880);            // 2560 B
    double* ssq      = (double*)(ws + 1149440);            // 2560 B
    double* partials = (double*)(ws + 1152000);            // 20480 B
    int*    counter  = (int*)(ws + 1172480);

    k_tr  <<<dim3(BSZ), dim3(256), 0, stream>>>(z, znT4, counter);
    k_gram<<<dim3(BSZ), dim3(BSZ), 0, stream>>>(z, znT4, E32, Kn32, rE, ssq);
    k_cf  <<<dim3(BSZ), dim3(BSZ), 0, stream>>>(E32, Kn32, rE, ssq, partials, counter, out);
}

// Round 9
// 29.212 us; speedup vs baseline: 1.9226x; 1.9226x over previous
//
#include <hip/hip_runtime.h>
#include <math.h>

#define BSZ 320
#define N2  640
#define DIM 128
#define GAMF 14.285714285714286f   // 1/0.07

__device__ __forceinline__ double wave_red(double v) {
    #pragma unroll
    for (int off = 32; off > 0; off >>= 1) v += __shfl_down(v, off, 64);
    return v;
}

// --- K1: fused norm + gram via LDS-staged z chunks; f32 throughout the hot loop.
// Block b owns rows i0=2b, i0+1. Writes E32 (=KK, zero diag), Kn32, rE, ssq (f64).
// Block 0 zeroes the ticket counter for K2. ---
__launch_bounds__(640)
__global__ void k_gram(const float* __restrict__ z, float* __restrict__ E32,
                       float* __restrict__ Kn32, double* __restrict__ rE,
                       double* __restrict__ ssq, int* __restrict__ counter) {
    const int j  = threadIdx.x;            // 640
    const int i0 = blockIdx.x * 2;         // 160 blocks
    __shared__ float  zc[N2][36];          // 32-k chunk; stride 144B keeps rows 16B-aligned
    __shared__ double sE[2][10], sQ[2][10];
    __shared__ float  szi[2];

    if (blockIdx.x == 0 && j == 0) *counter = 0;

    float rr  = 0.f;                       // own-row sum of squares (f32)
    float cr0 = 0.f, cr1 = 0.f;            // raw dots vs rows i0, i0+1

    for (int kc = 0; kc < 4; kc++) {
        const int k0 = kc * 32;
        __syncthreads();                   // protect zc reuse
        // stage: 5120 float4s, linear assignment -> coalesced global, clean LDS banks
        #pragma unroll
        for (int it = 0; it < 8; it++) {
            int f = it * 640 + j;          // 0..5119
            int row = f >> 3, c4 = f & 7;
            *(float4*)&zc[row][c4 * 4] = *(const float4*)(z + row * DIM + k0 + c4 * 4);
        }
        __syncthreads();
        #pragma unroll
        for (int k4 = 0; k4 < 8; k4++) {
            float4 b  = *(const float4*)&zc[j][k4 * 4];        // b128, bank-clean
            float4 a0 = *(const float4*)&zc[i0][k4 * 4];       // broadcast
            float4 a1 = *(const float4*)&zc[i0 + 1][k4 * 4];   // broadcast
            cr0 = fmaf(a0.x, b.x, cr0); cr1 = fmaf(a1.x, b.x, cr1); rr = fmaf(b.x, b.x, rr);
            cr0 = fmaf(a0.y, b.y, cr0); cr1 = fmaf(a1.y, b.y, cr1); rr = fmaf(b.y, b.y, rr);
            cr0 = fmaf(a0.z, b.z, cr0); cr1 = fmaf(a1.z, b.z, cr1); rr = fmaf(b.z, b.z, rr);
            cr0 = fmaf(a0.w, b.w, cr0); cr1 = fmaf(a1.w, b.w, cr1); rr = fmaf(b.w, b.w, rr);
        }
    }

    float sinv = 1.0f / sqrtf(rr);
    if (j == i0)     szi[0] = sinv;
    if (j == i0 + 1) szi[1] = sinv;
    __syncthreads();
    float c0 = cr0 * szi[0] * sinv;
    float c1 = cr1 * szi[1] * sinv;
    float v0 = __expf(-GAMF * (2.0f - 2.0f * c0));
    float v1 = __expf(-GAMF * (2.0f - 2.0f * c1));

    double e0 = 0.0, e1 = 0.0;
    if (j < BSZ) {
        float f0 = (j == i0    ) ? 0.f : v0;
        float f1 = (j == i0 + 1) ? 0.f : v1;
        E32[(i0    ) * BSZ + j] = f0;
        E32[(i0 + 1) * BSZ + j] = f1;
        e0 = (double)f0; e1 = (double)f1;
    } else {
        Kn32[(j - BSZ) * BSZ + i0    ] = v0;   // Kn32[j'][i] = K[i, 320+j']
        Kn32[(j - BSZ) * BSZ + i0 + 1] = v1;
    }
    double q0 = e0 * e0, q1 = e1 * e1;
    e0 = wave_red(e0); q0 = wave_red(q0);
    e1 = wave_red(e1); q1 = wave_red(q1);
    int wave = j >> 6, lane = j & 63;
    if (lane == 0) { sE[0][wave] = e0; sQ[0][wave] = q0; sE[1][wave] = e1; sQ[1][wave] = q1; }
    __syncthreads();
    if (j < 2) {
        double se = 0.0, sq = 0.0;
        for (int w = 0; w < 10; w++) { se += sE[j][w]; sq += sQ[j][w]; }
        rE[i0 + j] = se; ssq[i0 + j] = sq;
    }
}

// --- K2: per-t coef + final pass; non-atomic partials + ticket; last block outputs ---
__launch_bounds__(320)
__global__ void k_cf(const float* __restrict__ E32, const float* __restrict__ Kn32,
                     const double* __restrict__ rE, const double* __restrict__ ssq,
                     double* __restrict__ partials, int* __restrict__ counter,
                     float* __restrict__ out) {
    const int t = blockIdx.x, tid = threadIdx.x;   // 320 x 320
    const int wave = tid >> 6, lane = tid & 63;
    __shared__ double sred[5][7];
    __shared__ double sc[8];
    __shared__ int lastflag;
    const double a = 1.0 / 1.1, c = 1.0 / 321.1;
    const double q = 1.0 - 320.0 * c;

    double rEi  = rE[tid];
    double Ereg = (double)E32[t * BSZ + tid];
    double kn   = (double)Kn32[t * BSZ + tid];
    if (tid == t) sc[6] = kn;                      // posterm_t = K[t, 320+t]

    // block reduce: S = sum rE, mv = E[t,:].rE
    {
        double s1 = wave_red(rEi);
        double s2 = wave_red(Ereg * rEi);
        if (lane == 0) { sred[wave][0] = s1; sred[wave][1] = s2; }
    }
    __syncthreads();
    if (tid == 0) {
        double S = 0, mv = 0;
        for (int w = 0; w < 5; w++) { S += sred[w][0]; mv += sred[w][1]; }
        double rEt = rE[t], ssqt = ssq[t];
        double pt  = a * q - a * a * q * (rEt - c * S);
        double b   = 320.0 * a * q - a * a * q * q * S;
        double up  = a * q * rEt - a * a * q * (mv - c * S * rEt);
        double sc1 = a * ssqt - a * c * rEt * rEt;
        double Wtt = -a * c * rEt;
        double Mtt = a * (1.0 - c) - a * a * (c * c * S - 2.0 * c * rEt);
        double s11 = 1.0 - up, s12 = -b, s21 = -sc1, s22 = 1.0 - up;
        double det = s11 * s22 - s12 * s21;
        double r1 = 2.0 * b, r2 = 2.0 * up;
        double be1 = (s22 * r1 - s12 * r2) / det;
        double be2 = (s11 * r2 - s21 * r1) / det;
        double g1  = (s22 * pt - s12 * Wtt) / det;
        double g2  = (s11 * Wtt - s21 * pt) / det;
        double ytt = 2.0 * pt + be1 * Wtt + be2 * pt;
        double dt  = Mtt + g1 * Wtt + g2 * pt;
        double rho = ytt / dt;
        sc[0] = rEt;
        sc[1] = S;
        sc[2] = 2.0 + be2 - rho * g2;   // cP
        sc[3] = be1 - rho * g1;         // cW
        sc[4] = -rho;                   // cM
    }
    __syncthreads();

    // final per-(t, i=tid) pass
    {
        double rEt = sc[0], S = sc[1], cP = sc[2], cW = sc[3], cM = sc[4];
        double s_neg = 0, s_al = 0, s_kn = 0, cz = 0, c1v = 0, cpos = 0;
        if (tid != t) {
            double p_i = a * q - a * a * q * (rEi - c * S);
            double V   = a * Ereg - a * c * rEt;
            double Mi  = -a * c - a * a * (Ereg - c * (rEt + rEi) + c * c * S);
            double x = cP * p_i + cW * V + cM * Mi;
            double alpha = fmin(fmax(x, 0.0), 1.0);
            s_neg = alpha * kn; s_al = alpha; s_kn = kn;
            cz   = (x <= 0.0) ? 1.0 : 0.0;
            c1v  = (x >= 1.0) ? 1.0 : 0.0;
            cpos = (x > 0.0) ? 1.0 : 0.0;
        }
        s_neg = wave_red(s_neg); s_al = wave_red(s_al); s_kn = wave_red(s_kn);
        cz = wave_red(cz); c1v = wave_red(c1v); cpos = wave_red(cpos);
        if (lane == 0) {
            sred[wave][0] = s_neg; sred[wave][1] = s_al; sred[wave][2] = s_kn;
            sred[wave][3] = cz;    sred[wave][4] = c1v;  sred[wave][5] = cpos;
        }
    }
    __syncthreads();
    if (tid == 0) {
        double a0 = 0, a1 = 0, a2 = 0, a3 = 0, a4 = 0, a5 = 0;
        for (int w = 0; w < 5; w++) {
            a0 += sred[w][0]; a1 += sred[w][1]; a2 += sred[w][2];
            a3 += sred[w][3]; a4 += sred[w][4]; a5 += sred[w][5];
        }
        partials[t * 8 + 0] = a0;
        partials[t * 8 + 1] = a1 * sc[6];
        partials[t * 8 + 2] = a2;
        partials[t * 8 + 3] = a3;
        partials[t * 8 + 4] = a4;
        partials[t * 8 + 5] = a5;
        partials[t * 8 + 6] = sc[6];
        __threadfence();
        int ticket = atomicAdd(counter, 1);
        lastflag = (ticket == BSZ - 1) ? 1 : 0;
    }
    __syncthreads();

    // last block: global reduce of partials -> 6 f32 outputs
    if (lastflag) {
        __threadfence();
        double v0 = partials[tid * 8 + 0], v1 = partials[tid * 8 + 1];
        double v2 = partials[tid * 8 + 2], v3 = partials[tid * 8 + 3];
        double v4 = partials[tid * 8 + 4], v5 = partials[tid * 8 + 5];
        double v6 = partials[tid * 8 + 6];
        v0 = wave_red(v0); v1 = wave_red(v1); v2 = wave_red(v2);
        v3 = wave_red(v3); v4 = wave_red(v4); v5 = wave_red(v5);
        v6 = wave_red(v6);
        if (lane == 0) {
            sred[wave][0] = v0; sred[wave][1] = v1; sred[wave][2] = v2;
            sred[wave][3] = v3; sred[wave][4] = v4; sred[wave][5] = v5;
            sred[wave][6] = v6;
        }
        __syncthreads();
        if (tid == 0) {
            double b0 = 0, b1 = 0, b2 = 0, b3 = 0, b4 = 0, b5 = 0, b6 = 0;
            for (int w = 0; w < 5; w++) {
                b0 += sred[w][0]; b1 += sred[w][1]; b2 += sred[w][2];
                b3 += sred[w][3]; b4 += sred[w][4]; b5 += sred[w][5];
                b6 += sred[w][6];
            }
            out[0] = (float)((b0 - b1) / 320.0);        // loss
            out[1] = (float)(b6 / 320.0);               // pos_terms.mean()
            out[2] = (float)(b2 / (319.0 * 320.0));     // Kn.mean()
            out[3] = (float)(b4 / (b5 + 1e-10));        // sparsity
            out[4] = (float)(b3 / (320.0 * 319.0));     // num_zero
            out[5] = 0.0f;
        }
    }
}

extern "C" void kernel_launch(void* const* d_in, const int* in_sizes, int n_in,
                              void* d_out, int out_size, void* d_ws, size_t ws_size,
                              hipStream_t stream) {
    const float* z = (const float*)d_in[0];
    float* out = (float*)d_out;
    char* ws = (char*)d_ws;

    float*  E32      = (float*)(ws);                 // 409600 B
    float*  Kn32     = (float*)(ws + 409600);        // 409600 B
    double* rE       = (double*)(ws + 819200);       // 2560 B
    double* ssq      = (double*)(ws + 821760);       // 2560 B
    double* partials = (double*)(ws + 824320);       // 20480 B
    int*    counter  = (int*)(ws + 844800);

    k_gram<<<dim3(BSZ / 2), dim3(640), 0, stream>>>(z, E32, Kn32, rE, ssq, counter);
    k_cf  <<<dim3(BSZ), dim3(BSZ), 0, stream>>>(E32, Kn32, rE, ssq, partials, counter, out);
}